// Round 10
// baseline (174.399 us; speedup 1.0000x reference)
//
#include <hip/hip_runtime.h>

#define BB 2
#define NN 384
#define CC 1024
#define HR 256      // H_REPN
#define NHEADS 4
#define TOPK 8
#define CAP 448
#define NEG 0.2f

typedef __attribute__((ext_vector_type(8))) short bf16x8;
typedef __attribute__((ext_vector_type(4))) float f32x4;

__device__ __forceinline__ unsigned short f2bf(float v) {
    unsigned u = __float_as_uint(v);
    return (unsigned short)((u + 0x7FFFu + ((u >> 16) & 1u)) >> 16);
}
__device__ __forceinline__ float bf2f(unsigned short h) {
    return __uint_as_float((unsigned)h << 16);
}

// ---------------- merged prep: Asw, Bsw, Al, Bh/Bl, wgp, zero counts/xw2 ----------------
// block ranges: [0,396) prepa | [396,924) prepb-tiled | [924,1308) prep Al | [1308,1564) prepb2-tiled | 1564 wgp
__global__ __launch_bounds__(256) void k_prep(const float* __restrict__ feats,
        const float* __restrict__ boxes, const float* __restrict__ gat1_w,
        const float* __restrict__ fc1_w,
        uint4* __restrict__ Asw, uint4* __restrict__ Bsw,
        uint4* __restrict__ Al,
        uint4* __restrict__ Bh, uint4* __restrict__ Bl,
        float4* __restrict__ wgp, int* __restrict__ counts,
        float* __restrict__ xw2) {
    __shared__ float sw[32][65];
    int blk = blockIdx.x;
    int t = threadIdx.x;
    int gflat = blk * 256 + t;
    if (gflat < BB * NN) counts[gflat] = 0;
    if (gflat < BB * NN * 2) xw2[gflat] = 0.f;

    if (blk < 396) {                    // ---- prep A (bf16) for xw1 + p12-high (Kp=1056) ----
        int flat = gflat;
        int lane = flat & 63;
        int kc = (flat >> 6) % 33;
        int mt = flat / (33 * 64);
        int m = mt * 16 + (lane & 15);
        int k0 = kc * 32 + (lane >> 4) * 8;
        unsigned short vals[8];
        const float s = 1.0f / 800.0f;
#pragma unroll
        for (int j = 0; j < 8; j++) {
            int k = k0 + j;
            float v;
            if (k < CC) v = feats[(size_t)m * CC + k];
            else if (k < CC + 4) {
                const float* bx = boxes + (size_t)m * 4;
                int gk = k - CC;
                v = (gk == 0) ? bx[0] * s : (gk == 1) ? bx[1] * s
                  : (gk == 2) ? (bx[2] - bx[0]) * s : (bx[3] - bx[1]) * s;
            } else v = 0.f;
            vals[j] = f2bf(v);
        }
        uint4 pk;
        pk.x = (unsigned)vals[0] | ((unsigned)vals[1] << 16);
        pk.y = (unsigned)vals[2] | ((unsigned)vals[3] << 16);
        pk.z = (unsigned)vals[4] | ((unsigned)vals[5] << 16);
        pk.w = (unsigned)vals[6] | ((unsigned)vals[7] << 16);
        Asw[flat] = pk;
    } else if (blk < 924) {             // ---- prep B for xw1 (gat1_w) via LDS tile, coalesced ----
        int blkrel = blk - 396;          // ntg*33 + kc
        int ntg = blkrel / 33;
        int kc  = blkrel % 33;
        int k0 = kc * 32;
        int n0 = ntg * 64;
#pragma unroll
        for (int pass = 0; pass < 8; pass++) {
            int kl = pass * 4 + (t >> 6);
            int k = k0 + kl;
            int nl = t & 63;
            float v = (k < CC + 4) ? gat1_w[(size_t)k * 1024 + n0 + nl] : 0.f;
            sw[kl][nl] = v;
        }
        __syncthreads();
        int local_nt = t >> 6;
        int lane = t & 63;
        int nn = lane & 15;
        int q = lane >> 4;
        int nl = local_nt * 16 + nn;
        unsigned short vals[8];
#pragma unroll
        for (int j = 0; j < 8; j++) vals[j] = f2bf(sw[q * 8 + j][nl]);
        uint4 pk;
        pk.x = (unsigned)vals[0] | ((unsigned)vals[1] << 16);
        pk.y = (unsigned)vals[2] | ((unsigned)vals[3] << 16);
        pk.z = (unsigned)vals[4] | ((unsigned)vals[5] << 16);
        pk.w = (unsigned)vals[6] | ((unsigned)vals[7] << 16);
        int nt = ntg * 4 + local_nt;
        Bsw[(size_t)nt * 33 * 64 + kc * 64 + lane] = pk;
    } else if (blk < 1308) {            // ---- prep A low-part for p12 (feats), contiguous reads ----
        int flat = gflat - 924 * 256;
        int lane = flat & 63;
        int kc = (flat >> 6) % 32;
        int mt = flat / (32 * 64);
        int m = mt * 16 + (lane & 15);
        int k0 = kc * 32 + (lane >> 4) * 8;
        unsigned short vl[8];
        const float* src = feats + (size_t)m * CC + k0;
#pragma unroll
        for (int j = 0; j < 8; j++) {
            float v = src[j];
            unsigned short h = f2bf(v);
            vl[j] = f2bf(v - bf2f(h));
        }
        uint4 pl;
        pl.x = (unsigned)vl[0] | ((unsigned)vl[1] << 16);
        pl.y = (unsigned)vl[2] | ((unsigned)vl[3] << 16);
        pl.z = (unsigned)vl[4] | ((unsigned)vl[5] << 16);
        pl.w = (unsigned)vl[6] | ((unsigned)vl[7] << 16);
        Al[flat] = pl;
    } else if (blk < 1564) {            // ---- prep B hi/lo for p12 ([Wa|Wb]) via LDS tile ----
        int blkrel = blk - 1308;         // ntg*32 + kc
        int ntg = blkrel / 32;
        int kc  = blkrel % 32;
        int k0 = kc * 32;
        int n0 = ntg * 64;
#pragma unroll
        for (int pass = 0; pass < 8; pass++) {
            int kl = pass * 4 + (t >> 6);
            int k = k0 + kl;
            int n = n0 + (t & 63);
            float v = (n < 256) ? fc1_w[(size_t)k * 256 + n]
                                : fc1_w[(size_t)(CC + k) * 256 + (n - 256)];
            sw[kl][t & 63] = v;
        }
        __syncthreads();
        int local_nt = t >> 6;
        int lane = t & 63;
        int nn = lane & 15;
        int q = lane >> 4;
        int nl = local_nt * 16 + nn;
        unsigned short vh[8], vl[8];
#pragma unroll
        for (int j = 0; j < 8; j++) {
            float v = sw[q * 8 + j][nl];
            unsigned short h = f2bf(v);
            vh[j] = h;
            vl[j] = f2bf(v - bf2f(h));
        }
        uint4 ph, pl;
        ph.x = (unsigned)vh[0] | ((unsigned)vh[1] << 16);
        ph.y = (unsigned)vh[2] | ((unsigned)vh[3] << 16);
        ph.z = (unsigned)vh[4] | ((unsigned)vh[5] << 16);
        ph.w = (unsigned)vh[6] | ((unsigned)vh[7] << 16);
        pl.x = (unsigned)vl[0] | ((unsigned)vl[1] << 16);
        pl.y = (unsigned)vl[2] | ((unsigned)vl[3] << 16);
        pl.z = (unsigned)vl[4] | ((unsigned)vl[5] << 16);
        pl.w = (unsigned)vl[6] | ((unsigned)vl[7] << 16);
        int nt = ntg * 4 + local_nt;
        size_t o = (size_t)nt * 32 * 64 + kc * 64 + lane;
        Bh[o] = ph; Bl[o] = pl;
    } else {                            // ---- pack wg rows into float4 per c ----
        int c = t;
        float4 w;
        w.x = fc1_w[(size_t)(2 * CC + 0) * HR + c];
        w.y = fc1_w[(size_t)(2 * CC + 1) * HR + c];
        w.z = fc1_w[(size_t)(2 * CC + 2) * HR + c];
        w.w = fc1_w[(size_t)(2 * CC + 3) * HR + c];
        wgp[c] = w;
    }
}

// ---------------- merged MFMA, 2 m-tiles per block: [0,192) p12 | [192,576) xw1 ----------------
// p12 high-A comes from Asw (stride 33*64 per mt; bit-identical to the old Ah)
__global__ __launch_bounds__(512) void k_mm(const uint4* __restrict__ Asw,
        const uint4* __restrict__ Al, const uint4* __restrict__ Bh,
        const uint4* __restrict__ Bl, const float* __restrict__ fc1_b,
        float* __restrict__ p1, float* __restrict__ p2t,
        const uint4* __restrict__ Bsw, float* __restrict__ xw1) {
    __shared__ float lds[4][64][8];
    int t = threadIdx.x;
    int w = t >> 6;
    int lane = t & 63;
    int g = w & 3;                   // nt sub-group
    int kh = w >> 2;                 // K half
    int blk0 = blockIdx.x;
    if (blk0 < 192) {
        int mtp = blk0 >> 3;
        int nt = (blk0 & 7) * 4 + g;
        int mt0 = mtp * 2;
        f32x4 acc0 = {0.f, 0.f, 0.f, 0.f};
        f32x4 acc1 = {0.f, 0.f, 0.f, 0.f};
        const uint4* pah0 = Asw + (size_t)mt0 * 33 * 64 + (size_t)kh * 16 * 64 + lane;
        const uint4* pal0 = Al + (size_t)mt0 * 32 * 64 + (size_t)kh * 16 * 64 + lane;
        const uint4* pbh = Bh + (size_t)nt * 32 * 64 + (size_t)kh * 16 * 64 + lane;
        const uint4* pbl = Bl + (size_t)nt * 32 * 64 + (size_t)kh * 16 * 64 + lane;
#pragma unroll 2
        for (int kc = 0; kc < 16; kc++) {
            uint4 ah0 = pah0[kc * 64];
            uint4 al0 = pal0[kc * 64];
            uint4 ah1 = pah0[kc * 64 + 2112];   // next mt in Asw (33*64 stride)
            uint4 al1 = pal0[kc * 64 + 2048];   // next mt in Al (32*64 stride)
            uint4 bh = pbh[kc * 64];
            uint4 bl = pbl[kc * 64];
            acc0 = __builtin_amdgcn_mfma_f32_16x16x32_bf16(*(bf16x8*)&ah0, *(bf16x8*)&bh, acc0, 0, 0, 0);
            acc0 = __builtin_amdgcn_mfma_f32_16x16x32_bf16(*(bf16x8*)&ah0, *(bf16x8*)&bl, acc0, 0, 0, 0);
            acc0 = __builtin_amdgcn_mfma_f32_16x16x32_bf16(*(bf16x8*)&al0, *(bf16x8*)&bh, acc0, 0, 0, 0);
            acc1 = __builtin_amdgcn_mfma_f32_16x16x32_bf16(*(bf16x8*)&ah1, *(bf16x8*)&bh, acc1, 0, 0, 0);
            acc1 = __builtin_amdgcn_mfma_f32_16x16x32_bf16(*(bf16x8*)&ah1, *(bf16x8*)&bl, acc1, 0, 0, 0);
            acc1 = __builtin_amdgcn_mfma_f32_16x16x32_bf16(*(bf16x8*)&al1, *(bf16x8*)&bh, acc1, 0, 0, 0);
        }
        if (kh == 1) {
#pragma unroll
            for (int r = 0; r < 4; r++) { lds[g][lane][r] = acc0[r]; lds[g][lane][4 + r] = acc1[r]; }
        }
        __syncthreads();
        if (kh == 0) {
#pragma unroll
            for (int r = 0; r < 4; r++) { acc0[r] += lds[g][lane][r]; acc1[r] += lds[g][lane][4 + r]; }
            int col = nt * 16 + (lane & 15);
            int rbase = (lane >> 4) * 4;
            if (col < 256) {
                float bias = fc1_b[col];
#pragma unroll
                for (int r = 0; r < 4; r++) {
                    p1[(size_t)(mt0 * 16 + rbase + r) * 256 + col] = acc0[r] + bias;
                    p1[(size_t)(mt0 * 16 + 16 + rbase + r) * 256 + col] = acc1[r] + bias;
                }
            } else {
#pragma unroll
                for (int r = 0; r < 4; r++) {
                    int rr0 = mt0 * 16 + rbase + r;
                    int rr1 = rr0 + 16;
                    p2t[((size_t)(rr0 / NN) * 256 + (col - 256)) * NN + (rr0 % NN)] = acc0[r];
                    p2t[((size_t)(rr1 / NN) * 256 + (col - 256)) * NN + (rr1 % NN)] = acc1[r];
                }
            }
        }
    } else {
        int blk = blk0 - 192;
        int mtp = blk >> 4;
        int nt = (blk & 15) * 4 + g;
        int mt0 = mtp * 2;
        int nk = kh ? 16 : 17;
        f32x4 acc0 = {0.f, 0.f, 0.f, 0.f};
        f32x4 acc1 = {0.f, 0.f, 0.f, 0.f};
        const uint4* pa0 = Asw + (size_t)mt0 * 33 * 64 + (size_t)kh * 17 * 64 + lane;
        const uint4* pb = Bsw + (size_t)nt * 33 * 64 + (size_t)kh * 17 * 64 + lane;
#pragma unroll 4
        for (int kc = 0; kc < nk; kc++) {
            uint4 a0 = pa0[kc * 64];
            uint4 a1 = pa0[kc * 64 + 2112];
            uint4 bv = pb[kc * 64];
            acc0 = __builtin_amdgcn_mfma_f32_16x16x32_bf16(*(bf16x8*)&a0, *(bf16x8*)&bv, acc0, 0, 0, 0);
            acc1 = __builtin_amdgcn_mfma_f32_16x16x32_bf16(*(bf16x8*)&a1, *(bf16x8*)&bv, acc1, 0, 0, 0);
        }
        if (kh == 1) {
#pragma unroll
            for (int r = 0; r < 4; r++) { lds[g][lane][r] = acc0[r]; lds[g][lane][4 + r] = acc1[r]; }
        }
        __syncthreads();
        if (kh == 0) {
#pragma unroll
            for (int r = 0; r < 4; r++) { acc0[r] += lds[g][lane][r]; acc1[r] += lds[g][lane][4 + r]; }
            int col = nt * 16 + (lane & 15);
            int rbase = (lane >> 4) * 4;
#pragma unroll
            for (int r = 0; r < 4; r++) {
                xw1[(size_t)(mt0 * 16 + rbase + r) * 1024 + col] = acc0[r];
                xw1[(size_t)(mt0 * 16 + 16 + rbase + r) * 1024 + col] = acc1[r];
            }
        }
    }
}

// ---------------- merged: [0,384) rel(2 rows)+top8+scatter | [384,1152) att1 dots ----------------
__global__ __launch_bounds__(384) void k_relatt(const float* __restrict__ p1,
        const float* __restrict__ p2t, const float* __restrict__ boxes,
        const float4* __restrict__ wgp, const float* __restrict__ fc2_w,
        int* __restrict__ counts, int* __restrict__ inlist,
        const float* __restrict__ xw1, const float* __restrict__ att_src,
        const float* __restrict__ att_dst, float* __restrict__ a_s,
        float* __restrict__ a_d) {
    __shared__ float cv[2][48];
    __shared__ int   ci[2][48];
    int blk0 = blockIdx.x;
    if (blk0 < 384) {
        int b = blk0 / 192;
        int i0 = (blk0 - b * 192) * 2;
        int row0 = b * NN + i0;
        int j = threadIdx.x;
        int wid = j >> 6;
        int lane = j & 63;
        float a0 = boxes[(size_t)row0 * 4 + 0];
        float a1 = boxes[(size_t)row0 * 4 + 1];
        float a2 = boxes[(size_t)row0 * 4 + 2];
        float a3 = boxes[(size_t)row0 * 4 + 3];
        float c0 = boxes[(size_t)(row0 + 1) * 4 + 0];
        float c1 = boxes[(size_t)(row0 + 1) * 4 + 1];
        float c2 = boxes[(size_t)(row0 + 1) * 4 + 2];
        float c3 = boxes[(size_t)(row0 + 1) * 4 + 3];
        float4 bj = *(const float4*)(boxes + ((size_t)b * NN + j) * 4);
        float g00 = fabsf(a0 - bj.x), g01 = fabsf(a1 - bj.y);
        float g02 = fabsf(a2 - bj.z), g03 = fabsf(a3 - bj.w);
        float g10 = fabsf(c0 - bj.x), g11 = fabsf(c1 - bj.y);
        float g12 = fabsf(c2 - bj.z), g13 = fabsf(c3 - bj.w);
        const float* p1r0 = p1 + (size_t)row0 * HR;
        const float* p1r1 = p1r0 + HR;
        const float* p2b = p2t + (size_t)b * HR * NN + j;
        float acc0 = 0.f, acc1 = 0.f;
#pragma unroll 8
        for (int c = 0; c < HR; c++) {
            float4 w = wgp[c];           // wave-uniform -> s_load_dwordx4
            float pa = p1r0[c];          // wave-uniform -> s_load
            float pb = p1r1[c];
            float wc = fc2_w[c];
            float p2v = p2b[(size_t)c * NN];
            float v0 = pa + p2v + g00 * w.x + g01 * w.y + g02 * w.z + g03 * w.w;
            float v1 = pb + p2v + g10 * w.x + g11 * w.y + g12 * w.z + g13 * w.w;
            acc0 += fmaxf(v0, 0.f) * wc;
            acc1 += fmaxf(v1, 0.f) * wc;
        }
        if (j == i0) acc0 = -INFINITY;       // diag mask
        if (j == i0 + 1) acc1 = -INFINITY;
        // wave-local top-8 for each row (no barriers)
#pragma unroll
        for (int r = 0; r < 2; r++) {
            float val = r ? acc1 : acc0;
            int idx = j;
            for (int k = 0; k < TOPK; k++) {
                float bv = val; int bi = idx;
#pragma unroll
                for (int off = 32; off > 0; off >>= 1) {
                    float ov = __shfl_xor(bv, off);
                    int   oi = __shfl_xor(bi, off);
                    if (ov > bv || (ov == bv && oi < bi)) { bv = ov; bi = oi; }
                }
                if (lane == k) { cv[r][wid * 8 + k] = bv; ci[r][wid * 8 + k] = bi; }
                if (idx == bi) val = -INFINITY;
            }
        }
        __syncthreads();
        // final: wave 0 handles row 0, wave 1 handles row 1
        if (wid < 2) {
            int r = wid;
            float val = (lane < 48) ? cv[r][lane] : -INFINITY;
            int idx = (lane < 48) ? ci[r][lane] : NN;
            int mine = -1;
            for (int k = 0; k < TOPK; k++) {
                float bv = val; int bi = idx;
#pragma unroll
                for (int off = 32; off > 0; off >>= 1) {
                    float ov = __shfl_xor(bv, off);
                    int   oi = __shfl_xor(bi, off);
                    if (ov > bv || (ov == bv && oi < bi)) { bv = ov; bi = oi; }
                }
                if (lane == k) mine = bi;
                if (idx == bi) val = -INFINITY;
            }
            int i = i0 + r;
            int rowg = b * NN + i;
            if (lane < TOPK) {
                int tg = b * NN + mine;
                int q = atomicAdd(&counts[tg], 1);
                inlist[(size_t)tg * CAP + q] = i;
            } else if (lane == TOPK) {   // self loop
                int q = atomicAdd(&counts[rowg], 1);
                inlist[(size_t)rowg * CAP + q] = i;
            }
        }
    } else {
        int node = blk0 - 384;
        int t = threadIdx.x;
        if (t >= 256) return;
        int w = t >> 6;
        int lane = t & 63;
        const float4* xr = (const float4*)(xw1 + (size_t)node * 1024 + w * 256);
        const float4* sr = (const float4*)(att_src + w * 256);
        const float4* dr = (const float4*)(att_dst + w * 256);
        float4 x = xr[lane];
        float4 s = sr[lane];
        float4 d = dr[lane];
        float ps = x.x * s.x + x.y * s.y + x.z * s.z + x.w * s.w;
        float pd = x.x * d.x + x.y * d.y + x.z * d.z + x.w * d.w;
#pragma unroll
        for (int off = 32; off > 0; off >>= 1) {
            ps += __shfl_xor(ps, off);
            pd += __shfl_xor(pd, off);
        }
        if (lane == 0) {
            a_s[(size_t)node * NHEADS + w] = ps;
            a_d[(size_t)node * NHEADS + w] = pd;
        }
    }
}

// ---------------- GAT1 aggregation per (node,head) + fused GAT2 projection atomics ----------------
__global__ __launch_bounds__(256) void k_agg1h(const int* __restrict__ counts,
        const int* __restrict__ inlist, const float* __restrict__ a_s,
        const float* __restrict__ a_d, const float* __restrict__ xw1,
        const float* __restrict__ gat1_b, const float* __restrict__ w2,
        float* __restrict__ xw2) {
    __shared__ int slist[CAP];
    __shared__ float walpha[CAP];
    __shared__ float redp[8];
    int blk = blockIdx.x;            // node*4 + h
    int node = blk >> 2;
    int h = blk & 3;
    int b = node / NN;
    int t = threadIdx.x;
    int wid = t >> 6;
    int lane = t & 63;
    int deg = counts[node];
    for (int e = t; e < deg; e += 256) slist[e] = inlist[(size_t)node * CAP + e];
    __syncthreads();
    if (t < 64) {
        float ad = a_d[(size_t)node * NHEADS + h];
        float vals[7];
        int cnt = 0;
        float vmax = -INFINITY;
        for (int e = t; e < deg; e += 64) {
            float x = a_s[(size_t)(b * NN + slist[e]) * NHEADS + h] + ad;
            x = x >= 0.f ? x : NEG * x;
            vals[cnt++] = x;
            vmax = fmaxf(vmax, x);
        }
#pragma unroll
        for (int off = 32; off > 0; off >>= 1)
            vmax = fmaxf(vmax, __shfl_xor(vmax, off));
        float sum = 0.f;
        for (int i = 0; i < cnt; i++) {
            vals[i] = expf(vals[i] - vmax);
            sum += vals[i];
        }
#pragma unroll
        for (int off = 32; off > 0; off >>= 1)
            sum += __shfl_xor(sum, off);
        float inv = 1.f / fmaxf(sum, 1e-16f);
        cnt = 0;
        for (int e = t; e < deg; e += 64) walpha[e] = vals[cnt++] * inv;
    }
    __syncthreads();
    float acc = 0.f;
    for (int e = 0; e < deg; e++)
        acc += walpha[e] * xw1[(size_t)(b * NN + slist[e]) * 1024 + h * 256 + t];
    float o = fmaxf(acc + gat1_b[h * 256 + t], 0.f);
    int d = h * 256 + t;
    float p0 = o * w2[d * 2];
    float p1v = o * w2[d * 2 + 1];
#pragma unroll
    for (int off = 32; off > 0; off >>= 1) {
        p0 += __shfl_xor(p0, off);
        p1v += __shfl_xor(p1v, off);
    }
    if (lane == 0) { redp[wid] = p0; redp[4 + wid] = p1v; }
    __syncthreads();
    if (t == 0) {
        atomicAdd(&xw2[(size_t)node * 2],     redp[0] + redp[1] + redp[2] + redp[3]);
        atomicAdd(&xw2[(size_t)node * 2 + 1], redp[4] + redp[5] + redp[6] + redp[7]);
    }
}

// ---------------- GAT2 aggregation -> output (one wave per node; on-the-fly att dots) ----------------
__global__ __launch_bounds__(64) void k_agg2(const int* __restrict__ counts,
        const int* __restrict__ inlist, const float* __restrict__ xw2,
        const float* __restrict__ as2, const float* __restrict__ ad2,
        const float* __restrict__ b2, float* __restrict__ out) {
    int node = blockIdx.x;
    int b = node / NN;
    int lane = threadIdx.x;
    int deg = counts[node];
    float s0 = as2[0], s1 = as2[1];
    float d0 = ad2[0], d1 = ad2[1];
    float2 xwn = *(const float2*)(xw2 + (size_t)node * 2);
    float ad = xwn.x * d0 + xwn.y * d1;
    float vals[7], xs0[7], xs1[7];
    int cnt = 0;
    float vmax = -INFINITY;
    for (int e = lane; e < deg; e += 64) {
        int s = b * NN + inlist[(size_t)node * CAP + e];
        float2 xws = *(const float2*)(xw2 + (size_t)s * 2);
        float x = xws.x * s0 + xws.y * s1 + ad;
        x = x >= 0.f ? x : NEG * x;
        xs0[cnt] = xws.x; xs1[cnt] = xws.y; vals[cnt] = x; cnt++;
        vmax = fmaxf(vmax, x);
    }
#pragma unroll
    for (int off = 32; off > 0; off >>= 1)
        vmax = fmaxf(vmax, __shfl_xor(vmax, off));
    float sum = 0.f;
    for (int i = 0; i < cnt; i++) {
        vals[i] = expf(vals[i] - vmax);
        sum += vals[i];
    }
#pragma unroll
    for (int off = 32; off > 0; off >>= 1)
        sum += __shfl_xor(sum, off);
    float inv = 1.f / fmaxf(sum, 1e-16f);
    float a0 = 0.f, a1 = 0.f;
    for (int i = 0; i < cnt; i++) {
        a0 += vals[i] * xs0[i];
        a1 += vals[i] * xs1[i];
    }
#pragma unroll
    for (int off = 32; off > 0; off >>= 1) {
        a0 += __shfl_xor(a0, off);
        a1 += __shfl_xor(a1, off);
    }
    if (lane == 0) {
        out[(size_t)node * 2]     = a0 * inv + b2[0];
        out[(size_t)node * 2 + 1] = a1 * inv + b2[1];
    }
}

extern "C" void kernel_launch(void* const* d_in, const int* in_sizes, int n_in,
                              void* d_out, int out_size, void* d_ws, size_t ws_size,
                              hipStream_t stream) {
    const float* feats  = (const float*)d_in[0];
    const float* boxes  = (const float*)d_in[1];
    const float* fc1_w  = (const float*)d_in[2];
    const float* fc1_b  = (const float*)d_in[3];
    const float* fc2_w  = (const float*)d_in[4];
    const float* fc2_b  = (const float*)d_in[5];
    const float* gat1_w = (const float*)d_in[6];
    const float* g1as   = (const float*)d_in[7];
    const float* g1ad   = (const float*)d_in[8];
    const float* gat1_b = (const float*)d_in[9];
    const float* gat2_w = (const float*)d_in[10];
    const float* g2as   = (const float*)d_in[11];
    const float* g2ad   = (const float*)d_in[12];
    const float* gat2_b = (const float*)d_in[13];
    float* out = (float*)d_out;
    (void)fc2_b;   // constant offset: order-irrelevant for top-k; GAT consumes edges only

    char* ws = (char*)d_ws;
    size_t off = 0;
    auto alloc = [&](size_t bytes) -> void* {
        void* p = ws + off;
        off += (bytes + 255) / 256 * 256;
        return p;
    };
    int*   counts = (int*)alloc((size_t)BB * NN * 4);
    int*   inlist = (int*)alloc((size_t)BB * NN * CAP * 4);
    float* p1     = (float*)alloc((size_t)BB * NN * HR * 4);
    float* p2t    = (float*)alloc((size_t)BB * HR * NN * 4);
    float* xw1    = (float*)alloc((size_t)BB * NN * 1024 * 4);
    float* a_s1   = (float*)alloc((size_t)BB * NN * NHEADS * 4);
    float* a_d1   = (float*)alloc((size_t)BB * NN * NHEADS * 4);
    float* xw2    = (float*)alloc((size_t)BB * NN * 2 * 4);
    uint4* Asw    = (uint4*)alloc((size_t)48 * 33 * 64 * 16);
    uint4* Bsw    = (uint4*)alloc((size_t)64 * 33 * 64 * 16);
    uint4* Al     = (uint4*)alloc((size_t)48 * 32 * 64 * 16);
    uint4* Bh     = (uint4*)alloc((size_t)32 * 32 * 64 * 16);
    uint4* Bl     = (uint4*)alloc((size_t)32 * 32 * 64 * 16);
    float4* wgp   = (float4*)alloc((size_t)HR * 16);
    (void)ws_size; (void)in_sizes; (void)n_in; (void)out_size;

    k_prep<<<1565, 256, 0, stream>>>(feats, boxes, gat1_w, fc1_w,
                                     Asw, Bsw, Al, Bh, Bl, wgp, counts, xw2);
    k_mm<<<576, 512, 0, stream>>>(Asw, Al, Bh, Bl, fc1_b, p1, p2t, Bsw, xw1);
    k_relatt<<<1152, 384, 0, stream>>>(p1, p2t, boxes, wgp, fc2_w, counts, inlist,
                                       xw1, g1as, g1ad, a_s1, a_d1);
    k_agg1h<<<BB * NN * NHEADS, 256, 0, stream>>>(counts, inlist, a_s1, a_d1, xw1,
                                                  gat1_b, gat2_w, xw2);
    k_agg2<<<BB * NN, 64, 0, stream>>>(counts, inlist, xw2, g2as, g2ad, gat2_b, out);
}

// Round 11
// 160.438 us; speedup vs baseline: 1.0870x; 1.0870x over previous
//
#include <hip/hip_runtime.h>

#define BB 2
#define NN 384
#define CC 1024
#define HR 256      // H_REPN
#define NHEADS 4
#define TOPK 8
#define CAP 448
#define NEG 0.2f

typedef __attribute__((ext_vector_type(8))) short bf16x8;
typedef __attribute__((ext_vector_type(4))) float f32x4;

__device__ __forceinline__ unsigned short f2bf(float v) {
    unsigned u = __float_as_uint(v);
    return (unsigned short)((u + 0x7FFFu + ((u >> 16) & 1u)) >> 16);
}
__device__ __forceinline__ float bf2f(unsigned short h) {
    return __uint_as_float((unsigned)h << 16);
}

// ---------------- merged prep: Asw, Bsw, Ah/Al, Bh/Bl, wgp, zero counts/xw2 ----------------
// block ranges: [0,396) prepa | [396,924) prepb-tiled | [924,1308) prepa2 | [1308,1564) prepb2-tiled | 1564 wgp
__global__ __launch_bounds__(256) void k_prep(const float* __restrict__ feats,
        const float* __restrict__ boxes, const float* __restrict__ gat1_w,
        const float* __restrict__ fc1_w,
        uint4* __restrict__ Asw, uint4* __restrict__ Bsw,
        uint4* __restrict__ Ah, uint4* __restrict__ Al,
        uint4* __restrict__ Bh, uint4* __restrict__ Bl,
        float4* __restrict__ wgp, int* __restrict__ counts,
        float* __restrict__ xw2) {
    __shared__ float sw[32][65];
    int blk = blockIdx.x;
    int t = threadIdx.x;
    int gflat = blk * 256 + t;
    if (gflat < BB * NN) counts[gflat] = 0;
    if (gflat < BB * NN * 2) xw2[gflat] = 0.f;

    if (blk < 396) {                    // ---- prep A for xw1 (Kp=1056), contiguous reads ----
        int flat = gflat;
        int lane = flat & 63;
        int kc = (flat >> 6) % 33;
        int mt = flat / (33 * 64);
        int m = mt * 16 + (lane & 15);
        int k0 = kc * 32 + (lane >> 4) * 8;
        unsigned short vals[8];
        const float s = 1.0f / 800.0f;
#pragma unroll
        for (int j = 0; j < 8; j++) {
            int k = k0 + j;
            float v;
            if (k < CC) v = feats[(size_t)m * CC + k];
            else if (k < CC + 4) {
                const float* bx = boxes + (size_t)m * 4;
                int gk = k - CC;
                v = (gk == 0) ? bx[0] * s : (gk == 1) ? bx[1] * s
                  : (gk == 2) ? (bx[2] - bx[0]) * s : (bx[3] - bx[1]) * s;
            } else v = 0.f;
            vals[j] = f2bf(v);
        }
        uint4 pk;
        pk.x = (unsigned)vals[0] | ((unsigned)vals[1] << 16);
        pk.y = (unsigned)vals[2] | ((unsigned)vals[3] << 16);
        pk.z = (unsigned)vals[4] | ((unsigned)vals[5] << 16);
        pk.w = (unsigned)vals[6] | ((unsigned)vals[7] << 16);
        Asw[flat] = pk;
    } else if (blk < 924) {             // ---- prep B for xw1 (gat1_w) via LDS tile, coalesced ----
        int blkrel = blk - 396;          // ntg*33 + kc ; ntg in [0,16), kc in [0,33)
        int ntg = blkrel / 33;
        int kc  = blkrel % 33;
        int k0 = kc * 32;
        int n0 = ntg * 64;
        // load 32 x 64 tile coalesced (4 rows per pass)
#pragma unroll
        for (int pass = 0; pass < 8; pass++) {
            int kl = pass * 4 + (t >> 6);
            int k = k0 + kl;
            int nl = t & 63;
            float v = (k < CC + 4) ? gat1_w[(size_t)k * 1024 + n0 + nl] : 0.f;
            sw[kl][nl] = v;
        }
        __syncthreads();
        int local_nt = t >> 6;           // 0..3
        int lane = t & 63;
        int nn = lane & 15;
        int q = lane >> 4;
        int nl = local_nt * 16 + nn;
        unsigned short vals[8];
#pragma unroll
        for (int j = 0; j < 8; j++) vals[j] = f2bf(sw[q * 8 + j][nl]);
        uint4 pk;
        pk.x = (unsigned)vals[0] | ((unsigned)vals[1] << 16);
        pk.y = (unsigned)vals[2] | ((unsigned)vals[3] << 16);
        pk.z = (unsigned)vals[4] | ((unsigned)vals[5] << 16);
        pk.w = (unsigned)vals[6] | ((unsigned)vals[7] << 16);
        int nt = ntg * 4 + local_nt;
        Bsw[(size_t)nt * 33 * 64 + kc * 64 + lane] = pk;
    } else if (blk < 1308) {            // ---- prep A hi/lo for p12 (feats), contiguous reads ----
        int flat = gflat - 924 * 256;
        int lane = flat & 63;
        int kc = (flat >> 6) % 32;
        int mt = flat / (32 * 64);
        int m = mt * 16 + (lane & 15);
        int k0 = kc * 32 + (lane >> 4) * 8;
        unsigned short vh[8], vl[8];
        const float* src = feats + (size_t)m * CC + k0;
#pragma unroll
        for (int j = 0; j < 8; j++) {
            float v = src[j];
            unsigned short h = f2bf(v);
            vh[j] = h;
            vl[j] = f2bf(v - bf2f(h));
        }
        uint4 ph, pl;
        ph.x = (unsigned)vh[0] | ((unsigned)vh[1] << 16);
        ph.y = (unsigned)vh[2] | ((unsigned)vh[3] << 16);
        ph.z = (unsigned)vh[4] | ((unsigned)vh[5] << 16);
        ph.w = (unsigned)vh[6] | ((unsigned)vh[7] << 16);
        pl.x = (unsigned)vl[0] | ((unsigned)vl[1] << 16);
        pl.y = (unsigned)vl[2] | ((unsigned)vl[3] << 16);
        pl.z = (unsigned)vl[4] | ((unsigned)vl[5] << 16);
        pl.w = (unsigned)vl[6] | ((unsigned)vl[7] << 16);
        Ah[flat] = ph; Al[flat] = pl;
    } else if (blk < 1564) {            // ---- prep B hi/lo for p12 ([Wa|Wb]) via LDS tile ----
        int blkrel = blk - 1308;         // ntg*32 + kc ; ntg in [0,8), kc in [0,32)
        int ntg = blkrel / 32;
        int kc  = blkrel % 32;
        int k0 = kc * 32;
        int n0 = ntg * 64;               // 64-col segment, entirely within Wa (n<256) or Wb
#pragma unroll
        for (int pass = 0; pass < 8; pass++) {
            int kl = pass * 4 + (t >> 6);
            int k = k0 + kl;
            int n = n0 + (t & 63);
            float v = (n < 256) ? fc1_w[(size_t)k * 256 + n]
                                : fc1_w[(size_t)(CC + k) * 256 + (n - 256)];
            sw[kl][t & 63] = v;
        }
        __syncthreads();
        int local_nt = t >> 6;
        int lane = t & 63;
        int nn = lane & 15;
        int q = lane >> 4;
        int nl = local_nt * 16 + nn;
        unsigned short vh[8], vl[8];
#pragma unroll
        for (int j = 0; j < 8; j++) {
            float v = sw[q * 8 + j][nl];
            unsigned short h = f2bf(v);
            vh[j] = h;
            vl[j] = f2bf(v - bf2f(h));
        }
        uint4 ph, pl;
        ph.x = (unsigned)vh[0] | ((unsigned)vh[1] << 16);
        ph.y = (unsigned)vh[2] | ((unsigned)vh[3] << 16);
        ph.z = (unsigned)vh[4] | ((unsigned)vh[5] << 16);
        ph.w = (unsigned)vh[6] | ((unsigned)vh[7] << 16);
        pl.x = (unsigned)vl[0] | ((unsigned)vl[1] << 16);
        pl.y = (unsigned)vl[2] | ((unsigned)vl[3] << 16);
        pl.z = (unsigned)vl[4] | ((unsigned)vl[5] << 16);
        pl.w = (unsigned)vl[6] | ((unsigned)vl[7] << 16);
        int nt = ntg * 4 + local_nt;
        size_t o = (size_t)nt * 32 * 64 + kc * 64 + lane;
        Bh[o] = ph; Bl[o] = pl;
    } else {                            // ---- pack wg rows into float4 per c ----
        int c = t;
        float4 w;
        w.x = fc1_w[(size_t)(2 * CC + 0) * HR + c];
        w.y = fc1_w[(size_t)(2 * CC + 1) * HR + c];
        w.z = fc1_w[(size_t)(2 * CC + 2) * HR + c];
        w.w = fc1_w[(size_t)(2 * CC + 3) * HR + c];
        wgp[c] = w;
    }
}

// ---------------- merged MFMA, 2 m-tiles per block: [0,192) p12 | [192,576) xw1 ----------------
__global__ __launch_bounds__(512) void k_mm(const uint4* __restrict__ Ah,
        const uint4* __restrict__ Al, const uint4* __restrict__ Bh,
        const uint4* __restrict__ Bl, const float* __restrict__ fc1_b,
        float* __restrict__ p1, float* __restrict__ p2t,
        const uint4* __restrict__ Asw, const uint4* __restrict__ Bsw,
        float* __restrict__ xw1) {
    __shared__ float lds[4][64][8];
    int t = threadIdx.x;
    int w = t >> 6;
    int lane = t & 63;
    int g = w & 3;                   // nt sub-group
    int kh = w >> 2;                 // K half
    int blk0 = blockIdx.x;
    if (blk0 < 192) {
        // ---- p1/p2 split-bf16 MFMA, 2 mt per block, K split 2x16 ----
        int mtp = blk0 >> 3;         // 0..23
        int nt = (blk0 & 7) * 4 + g;
        int mt0 = mtp * 2;
        f32x4 acc0 = {0.f, 0.f, 0.f, 0.f};
        f32x4 acc1 = {0.f, 0.f, 0.f, 0.f};
        const uint4* pah0 = Ah + (size_t)mt0 * 32 * 64 + (size_t)kh * 16 * 64 + lane;
        const uint4* pal0 = Al + (size_t)mt0 * 32 * 64 + (size_t)kh * 16 * 64 + lane;
        const uint4* pbh = Bh + (size_t)nt * 32 * 64 + (size_t)kh * 16 * 64 + lane;
        const uint4* pbl = Bl + (size_t)nt * 32 * 64 + (size_t)kh * 16 * 64 + lane;
#pragma unroll 2
        for (int kc = 0; kc < 16; kc++) {
            uint4 ah0 = pah0[kc * 64];
            uint4 al0 = pal0[kc * 64];
            uint4 ah1 = pah0[kc * 64 + 2048];
            uint4 al1 = pal0[kc * 64 + 2048];
            uint4 bh = pbh[kc * 64];
            uint4 bl = pbl[kc * 64];
            acc0 = __builtin_amdgcn_mfma_f32_16x16x32_bf16(*(bf16x8*)&ah0, *(bf16x8*)&bh, acc0, 0, 0, 0);
            acc0 = __builtin_amdgcn_mfma_f32_16x16x32_bf16(*(bf16x8*)&ah0, *(bf16x8*)&bl, acc0, 0, 0, 0);
            acc0 = __builtin_amdgcn_mfma_f32_16x16x32_bf16(*(bf16x8*)&al0, *(bf16x8*)&bh, acc0, 0, 0, 0);
            acc1 = __builtin_amdgcn_mfma_f32_16x16x32_bf16(*(bf16x8*)&ah1, *(bf16x8*)&bh, acc1, 0, 0, 0);
            acc1 = __builtin_amdgcn_mfma_f32_16x16x32_bf16(*(bf16x8*)&ah1, *(bf16x8*)&bl, acc1, 0, 0, 0);
            acc1 = __builtin_amdgcn_mfma_f32_16x16x32_bf16(*(bf16x8*)&al1, *(bf16x8*)&bh, acc1, 0, 0, 0);
        }
        if (kh == 1) {
#pragma unroll
            for (int r = 0; r < 4; r++) { lds[g][lane][r] = acc0[r]; lds[g][lane][4 + r] = acc1[r]; }
        }
        __syncthreads();
        if (kh == 0) {
#pragma unroll
            for (int r = 0; r < 4; r++) { acc0[r] += lds[g][lane][r]; acc1[r] += lds[g][lane][4 + r]; }
            int col = nt * 16 + (lane & 15);
            int rbase = (lane >> 4) * 4;
            if (col < 256) {
                float bias = fc1_b[col];
#pragma unroll
                for (int r = 0; r < 4; r++) {
                    p1[(size_t)(mt0 * 16 + rbase + r) * 256 + col] = acc0[r] + bias;
                    p1[(size_t)(mt0 * 16 + 16 + rbase + r) * 256 + col] = acc1[r] + bias;
                }
            } else {
#pragma unroll
                for (int r = 0; r < 4; r++) {
                    int rr0 = mt0 * 16 + rbase + r;
                    int rr1 = rr0 + 16;
                    p2t[((size_t)(rr0 / NN) * 256 + (col - 256)) * NN + (rr0 % NN)] = acc0[r];
                    p2t[((size_t)(rr1 / NN) * 256 + (col - 256)) * NN + (rr1 % NN)] = acc1[r];
                }
            }
        }
    } else {
        // ---- xw1 MFMA bf16, 2 mt per block, K split 17+16 ----
        int blk = blk0 - 192;        // mtp*16 + ntgrp
        int mtp = blk >> 4;
        int nt = (blk & 15) * 4 + g;
        int mt0 = mtp * 2;
        int nk = kh ? 16 : 17;
        f32x4 acc0 = {0.f, 0.f, 0.f, 0.f};
        f32x4 acc1 = {0.f, 0.f, 0.f, 0.f};
        const uint4* pa0 = Asw + (size_t)mt0 * 33 * 64 + (size_t)kh * 17 * 64 + lane;
        const uint4* pb = Bsw + (size_t)nt * 33 * 64 + (size_t)kh * 17 * 64 + lane;
#pragma unroll 4
        for (int kc = 0; kc < nk; kc++) {
            uint4 a0 = pa0[kc * 64];
            uint4 a1 = pa0[kc * 64 + 2112];
            uint4 bv = pb[kc * 64];
            acc0 = __builtin_amdgcn_mfma_f32_16x16x32_bf16(*(bf16x8*)&a0, *(bf16x8*)&bv, acc0, 0, 0, 0);
            acc1 = __builtin_amdgcn_mfma_f32_16x16x32_bf16(*(bf16x8*)&a1, *(bf16x8*)&bv, acc1, 0, 0, 0);
        }
        if (kh == 1) {
#pragma unroll
            for (int r = 0; r < 4; r++) { lds[g][lane][r] = acc0[r]; lds[g][lane][4 + r] = acc1[r]; }
        }
        __syncthreads();
        if (kh == 0) {
#pragma unroll
            for (int r = 0; r < 4; r++) { acc0[r] += lds[g][lane][r]; acc1[r] += lds[g][lane][4 + r]; }
            int col = nt * 16 + (lane & 15);
            int rbase = (lane >> 4) * 4;
#pragma unroll
            for (int r = 0; r < 4; r++) {
                xw1[(size_t)(mt0 * 16 + rbase + r) * 1024 + col] = acc0[r];
                xw1[(size_t)(mt0 * 16 + 16 + rbase + r) * 1024 + col] = acc1[r];
            }
        }
    }
}

// ---------------- merged: [0,768) rel partials | [768,1536) att1 dots ----------------
__global__ __launch_bounds__(384) void k_relatt(const float* __restrict__ p1,
        const float* __restrict__ p2t, const float* __restrict__ boxes,
        const float4* __restrict__ wgp, const float* __restrict__ fc2_w,
        float* __restrict__ rel_a, float* __restrict__ rel_b,
        const float* __restrict__ xw1, const float* __restrict__ att_src,
        const float* __restrict__ att_dst, float* __restrict__ a_s,
        float* __restrict__ a_d) {
    int blk0 = blockIdx.x;
    if (blk0 < 768) {
        int blk = blk0;
        int p = blk >> 1;
        int ch = blk & 1;
        int b = p / (NN / 2);
        int i0 = (p - b * (NN / 2)) * 2;
        int row0 = b * NN + i0;
        int j = threadIdx.x;
        float a0 = boxes[(size_t)row0 * 4 + 0];
        float a1 = boxes[(size_t)row0 * 4 + 1];
        float a2 = boxes[(size_t)row0 * 4 + 2];
        float a3 = boxes[(size_t)row0 * 4 + 3];
        float c0 = boxes[(size_t)(row0 + 1) * 4 + 0];
        float c1 = boxes[(size_t)(row0 + 1) * 4 + 1];
        float c2 = boxes[(size_t)(row0 + 1) * 4 + 2];
        float c3 = boxes[(size_t)(row0 + 1) * 4 + 3];
        float4 bj = *(const float4*)(boxes + ((size_t)b * NN + j) * 4);
        float g00 = fabsf(a0 - bj.x), g01 = fabsf(a1 - bj.y);
        float g02 = fabsf(a2 - bj.z), g03 = fabsf(a3 - bj.w);
        float g10 = fabsf(c0 - bj.x), g11 = fabsf(c1 - bj.y);
        float g12 = fabsf(c2 - bj.z), g13 = fabsf(c3 - bj.w);
        const float* p1r0 = p1 + (size_t)row0 * HR + ch * 128;
        const float* p1r1 = p1r0 + HR;
        const float* p2b = p2t + (size_t)b * HR * NN + (size_t)ch * 128 * NN + j;
        const float4* wg = wgp + ch * 128;
        const float* w2 = fc2_w + ch * 128;
        float acc0 = 0.f, acc1 = 0.f;
#pragma unroll 8
        for (int c = 0; c < 128; c++) {
            float4 w = wg[c];            // wave-uniform -> s_load_dwordx4
            float pa = p1r0[c];          // wave-uniform -> s_load
            float pb = p1r1[c];
            float wc = w2[c];
            float p2v = p2b[(size_t)c * NN];
            float v0 = pa + p2v + g00 * w.x + g01 * w.y + g02 * w.z + g03 * w.w;
            float v1 = pb + p2v + g10 * w.x + g11 * w.y + g12 * w.z + g13 * w.w;
            acc0 += fmaxf(v0, 0.f) * wc;
            acc1 += fmaxf(v1, 0.f) * wc;
        }
        float* dst = ch ? rel_b : rel_a;
        dst[(size_t)row0 * NN + j] = acc0;
        dst[(size_t)(row0 + 1) * NN + j] = acc1;
    } else {
        int node = blk0 - 768;
        int t = threadIdx.x;
        if (t >= 256) return;
        int w = t >> 6;
        int lane = t & 63;
        const float4* xr = (const float4*)(xw1 + (size_t)node * 1024 + w * 256);
        const float4* sr = (const float4*)(att_src + w * 256);
        const float4* dr = (const float4*)(att_dst + w * 256);
        float4 x = xr[lane];
        float4 s = sr[lane];
        float4 d = dr[lane];
        float ps = x.x * s.x + x.y * s.y + x.z * s.z + x.w * s.w;
        float pd = x.x * d.x + x.y * d.y + x.z * d.z + x.w * d.w;
#pragma unroll
        for (int off = 32; off > 0; off >>= 1) {
            ps += __shfl_xor(ps, off);
            pd += __shfl_xor(pd, off);
        }
        if (lane == 0) {
            a_s[(size_t)node * NHEADS + w] = ps;
            a_d[(size_t)node * NHEADS + w] = pd;
        }
    }
}

// ---------------- top-8 per row + edge scatter (sums partials, masks diag) ----------------
__global__ __launch_bounds__(64) void k_topk_inv(const float* __restrict__ rel_a,
        const float* __restrict__ rel_b, int* __restrict__ counts,
        int* __restrict__ inlist) {
    int row = blockIdx.x;            // b*N+i
    int b = row / NN;
    int i = row - b * NN;
    int t = threadIdx.x;
    const float* ra = rel_a + (size_t)row * NN;
    const float* rb = rel_b + (size_t)row * NN;
    float v[6]; int id[6];
#pragma unroll
    for (int q = 0; q < 6; q++) {
        int j = t + q * 64;
        float val = ra[j] + rb[j];
        if (j == i) val = -INFINITY;   // diag mask (== reference's -1e6)
        v[q] = val; id[q] = j;
    }
    int mine = -1;
    for (int k = 0; k < TOPK; k++) {
        float bv = -INFINITY; int bi = NN;
#pragma unroll
        for (int q = 0; q < 6; q++) {
            if (v[q] > bv || (v[q] == bv && id[q] < bi)) { bv = v[q]; bi = id[q]; }
        }
        for (int off = 32; off > 0; off >>= 1) {
            float ov = __shfl_down(bv, off);
            int   oi = __shfl_down(bi, off);
            if (ov > bv || (ov == bv && oi < bi)) { bv = ov; bi = oi; }
        }
        bi = __shfl(bi, 0);
        if (t == k) mine = bi;
#pragma unroll
        for (int q = 0; q < 6; q++) if (id[q] == bi) v[q] = -INFINITY;
    }
    if (t < TOPK) {
        int tg = b * NN + mine;
        int q = atomicAdd(&counts[tg], 1);
        inlist[(size_t)tg * CAP + q] = i;
    } else if (t == TOPK) {          // self loop
        int q = atomicAdd(&counts[row], 1);
        inlist[(size_t)row * CAP + q] = i;
    }
}

// ---------------- GAT1 aggregation per (node,head) + fused GAT2 projection atomics ----------------
__global__ __launch_bounds__(256) void k_agg1h(const int* __restrict__ counts,
        const int* __restrict__ inlist, const float* __restrict__ a_s,
        const float* __restrict__ a_d, const float* __restrict__ xw1,
        const float* __restrict__ gat1_b, const float* __restrict__ w2,
        float* __restrict__ xw2) {
    __shared__ int slist[CAP];
    __shared__ float walpha[CAP];
    __shared__ float redp[8];
    int blk = blockIdx.x;            // node*4 + h
    int node = blk >> 2;
    int h = blk & 3;
    int b = node / NN;
    int t = threadIdx.x;
    int wid = t >> 6;
    int lane = t & 63;
    int deg = counts[node];
    for (int e = t; e < deg; e += 256) slist[e] = inlist[(size_t)node * CAP + e];
    __syncthreads();
    if (t < 64) {
        float ad = a_d[(size_t)node * NHEADS + h];
        float vals[7];
        int cnt = 0;
        float vmax = -INFINITY;
        for (int e = t; e < deg; e += 64) {
            float x = a_s[(size_t)(b * NN + slist[e]) * NHEADS + h] + ad;
            x = x >= 0.f ? x : NEG * x;
            vals[cnt++] = x;
            vmax = fmaxf(vmax, x);
        }
#pragma unroll
        for (int off = 32; off > 0; off >>= 1)
            vmax = fmaxf(vmax, __shfl_xor(vmax, off));
        float sum = 0.f;
        for (int i = 0; i < cnt; i++) {
            vals[i] = expf(vals[i] - vmax);
            sum += vals[i];
        }
#pragma unroll
        for (int off = 32; off > 0; off >>= 1)
            sum += __shfl_xor(sum, off);
        float inv = 1.f / fmaxf(sum, 1e-16f);
        cnt = 0;
        for (int e = t; e < deg; e += 64) walpha[e] = vals[cnt++] * inv;
    }
    __syncthreads();
    float acc = 0.f;
    for (int e = 0; e < deg; e++)
        acc += walpha[e] * xw1[(size_t)(b * NN + slist[e]) * 1024 + h * 256 + t];
    float o = fmaxf(acc + gat1_b[h * 256 + t], 0.f);
    int d = h * 256 + t;
    float p0 = o * w2[d * 2];
    float p1v = o * w2[d * 2 + 1];
#pragma unroll
    for (int off = 32; off > 0; off >>= 1) {
        p0 += __shfl_xor(p0, off);
        p1v += __shfl_xor(p1v, off);
    }
    if (lane == 0) { redp[wid] = p0; redp[4 + wid] = p1v; }
    __syncthreads();
    if (t == 0) {
        atomicAdd(&xw2[(size_t)node * 2],     redp[0] + redp[1] + redp[2] + redp[3]);
        atomicAdd(&xw2[(size_t)node * 2 + 1], redp[4] + redp[5] + redp[6] + redp[7]);
    }
}

// ---------------- GAT2 aggregation -> output (one wave per node; on-the-fly att dots) ----------------
__global__ __launch_bounds__(64) void k_agg2(const int* __restrict__ counts,
        const int* __restrict__ inlist, const float* __restrict__ xw2,
        const float* __restrict__ as2, const float* __restrict__ ad2,
        const float* __restrict__ b2, float* __restrict__ out) {
    int node = blockIdx.x;
    int b = node / NN;
    int lane = threadIdx.x;
    int deg = counts[node];
    float s0 = as2[0], s1 = as2[1];
    float d0 = ad2[0], d1 = ad2[1];
    float2 xwn = *(const float2*)(xw2 + (size_t)node * 2);
    float ad = xwn.x * d0 + xwn.y * d1;
    float vals[7], xs0[7], xs1[7];
    int cnt = 0;
    float vmax = -INFINITY;
    for (int e = lane; e < deg; e += 64) {
        int s = b * NN + inlist[(size_t)node * CAP + e];
        float2 xws = *(const float2*)(xw2 + (size_t)s * 2);
        float x = xws.x * s0 + xws.y * s1 + ad;
        x = x >= 0.f ? x : NEG * x;
        xs0[cnt] = xws.x; xs1[cnt] = xws.y; vals[cnt] = x; cnt++;
        vmax = fmaxf(vmax, x);
    }
#pragma unroll
    for (int off = 32; off > 0; off >>= 1)
        vmax = fmaxf(vmax, __shfl_xor(vmax, off));
    float sum = 0.f;
    for (int i = 0; i < cnt; i++) {
        vals[i] = expf(vals[i] - vmax);
        sum += vals[i];
    }
#pragma unroll
    for (int off = 32; off > 0; off >>= 1)
        sum += __shfl_xor(sum, off);
    float inv = 1.f / fmaxf(sum, 1e-16f);
    float a0 = 0.f, a1 = 0.f;
    for (int i = 0; i < cnt; i++) {
        a0 += vals[i] * xs0[i];
        a1 += vals[i] * xs1[i];
    }
#pragma unroll
    for (int off = 32; off > 0; off >>= 1) {
        a0 += __shfl_xor(a0, off);
        a1 += __shfl_xor(a1, off);
    }
    if (lane == 0) {
        out[(size_t)node * 2]     = a0 * inv + b2[0];
        out[(size_t)node * 2 + 1] = a1 * inv + b2[1];
    }
}

extern "C" void kernel_launch(void* const* d_in, const int* in_sizes, int n_in,
                              void* d_out, int out_size, void* d_ws, size_t ws_size,
                              hipStream_t stream) {
    const float* feats  = (const float*)d_in[0];
    const float* boxes  = (const float*)d_in[1];
    const float* fc1_w  = (const float*)d_in[2];
    const float* fc1_b  = (const float*)d_in[3];
    const float* fc2_w  = (const float*)d_in[4];
    const float* fc2_b  = (const float*)d_in[5];
    const float* gat1_w = (const float*)d_in[6];
    const float* g1as   = (const float*)d_in[7];
    const float* g1ad   = (const float*)d_in[8];
    const float* gat1_b = (const float*)d_in[9];
    const float* gat2_w = (const float*)d_in[10];
    const float* g2as   = (const float*)d_in[11];
    const float* g2ad   = (const float*)d_in[12];
    const float* gat2_b = (const float*)d_in[13];
    float* out = (float*)d_out;
    (void)fc2_b;   // constant offset: order-irrelevant for top-k; GAT consumes edges only

    char* ws = (char*)d_ws;
    size_t off = 0;
    auto alloc = [&](size_t bytes) -> void* {
        void* p = ws + off;
        off += (bytes + 255) / 256 * 256;
        return p;
    };
    int*   counts = (int*)alloc((size_t)BB * NN * 4);
    int*   inlist = (int*)alloc((size_t)BB * NN * CAP * 4);
    float* p1     = (float*)alloc((size_t)BB * NN * HR * 4);
    float* p2t    = (float*)alloc((size_t)BB * HR * NN * 4);
    float* rel_a  = (float*)alloc((size_t)BB * NN * NN * 4);
    float* rel_b  = (float*)alloc((size_t)BB * NN * NN * 4);
    float* xw1    = (float*)alloc((size_t)BB * NN * 1024 * 4);
    float* a_s1   = (float*)alloc((size_t)BB * NN * NHEADS * 4);
    float* a_d1   = (float*)alloc((size_t)BB * NN * NHEADS * 4);
    float* xw2    = (float*)alloc((size_t)BB * NN * 2 * 4);
    uint4* Asw    = (uint4*)alloc((size_t)48 * 33 * 64 * 16);
    uint4* Bsw    = (uint4*)alloc((size_t)64 * 33 * 64 * 16);
    uint4* Ah     = (uint4*)alloc((size_t)48 * 32 * 64 * 16);
    uint4* Al     = (uint4*)alloc((size_t)48 * 32 * 64 * 16);
    uint4* Bh     = (uint4*)alloc((size_t)32 * 32 * 64 * 16);
    uint4* Bl     = (uint4*)alloc((size_t)32 * 32 * 64 * 16);
    float4* wgp   = (float4*)alloc((size_t)HR * 16);
    (void)ws_size; (void)in_sizes; (void)n_in; (void)out_size;

    k_prep<<<1565, 256, 0, stream>>>(feats, boxes, gat1_w, fc1_w,
                                     Asw, Bsw, Ah, Al, Bh, Bl, wgp, counts, xw2);
    k_mm<<<576, 512, 0, stream>>>(Ah, Al, Bh, Bl, fc1_b, p1, p2t, Asw, Bsw, xw1);
    k_relatt<<<1536, 384, 0, stream>>>(p1, p2t, boxes, wgp, fc2_w, rel_a, rel_b,
                                       xw1, g1as, g1ad, a_s1, a_d1);
    k_topk_inv<<<BB * NN, 64, 0, stream>>>(rel_a, rel_b, counts, inlist);
    k_agg1h<<<BB * NN * NHEADS, 256, 0, stream>>>(counts, inlist, a_s1, a_d1, xw1,
                                                  gat1_b, gat2_w, xw2);
    k_agg2<<<BB * NN, 64, 0, stream>>>(counts, inlist, xw2, g2as, g2ad, gat2_b, out);
}